// Round 10
// baseline (89.169 us; speedup 1.0000x reference)
//
#include <hip/hip_runtime.h>
#include <hip/hip_bf16.h>
#include <math.h>

#define S_   128
#define A_   14
#define DIM  32
#define EDGE 128
#define NPAIR 196         // A*A
#define NPOS  42          // A*3
#define NTASK 238         // NPAIR + NPOS
#define RB 16
#define DB 40
#define PB 64
#define NCLS 441
#define NPID (S_*S_)

// ---- f16 arena: 4-row units. Unit = [o2(16)][d(2)][j(4)] = 128 f16 = 256 B.
// Unit u covers rows rlo..rlo+3; element (o2,d,j) = dim 2*o2+d, row rlo+j.
#define SW_U 7            // rows 2u..2u+3, u=0..6  (R+D rows 0..15)
#define DW_U 12           // rows 14+2u..17+2u      (D rows 14..39, + R[15])
#define PW_U 31           // rows 2u..2u+3          (P rows 0..63)
#define AR_SW   0
#define AR_DW   (AR_SW + NPAIR*SW_U*128)
#define AR_RSH  (AR_DW + NPAIR*DW_U*128)    // R rows 12..15, 1 unit/task
#define AR_DSH  (AR_RSH + NPAIR*128)        // D rows 14..17, 1 unit/task
#define AR_PW   (AR_DSH + NPAIR*128)
#define AR_TOT  (AR_PW + NPOS*PW_U*128)     // 693504 f16 = 1.39 MB

// ---- ws layout (float units)
#define OFF_G      0
#define OFF_ARENA  (OFF_G + NCLS*DIM*EDGE)     // f16 arena

#define MAXJOBS (NTASK + NPAIR)
#define NGBLK   112        // 28 class-groups x 4 j-quarters
#define NPRE    (NTASK + NGBLK)

typedef _Float16 h2 __attribute__((ext_vector_type(2)));

#if defined(__has_builtin)
#if __has_builtin(__builtin_amdgcn_fdot2)
#define HAVE_FDOT2 1
#endif
#endif

__device__ __forceinline__ float fdot2f(unsigned int a, unsigned int b, float c) {
    h2 ha = __builtin_bit_cast(h2, a), hb = __builtin_bit_cast(h2, b);
#ifdef HAVE_FDOT2
    return __builtin_amdgcn_fdot2(ha, hb, c, false);
#else
    return c + (float)ha[0]*(float)hb[0] + (float)ha[1]*(float)hb[1];
#endif
}

__device__ __forceinline__ unsigned int pack2(float lo, float hi) {
    _Float16 l = (_Float16)lo, h = (_Float16)hi;
    unsigned short lu = __builtin_bit_cast(unsigned short, l);
    unsigned short hu = __builtin_bit_cast(unsigned short, h);
    return (unsigned int)lu | ((unsigned int)hu << 16);
}

// ---------------------------------------------------------------------------
// Fused preprocessing: blocks 0..195 pair tables, 196..237 pos tables,
// 238..349 G (16-class x 8-j tiles). (Class sort removed: R9 showed its
// L2-locality benefit ~1.7us vs ~10-15us serial-sort critical path.)
// Pair/pos compute: stage E[k][m] = emb+bias in LDS (padded 33), then
// thread=(k, o-quad) does float4 Wl-row loads + 4 FMA per m (2 k-rounds).
// ---------------------------------------------------------------------------
__global__ __launch_bounds__(256) void preproc(
    const float* __restrict__ aa_emb, const float* __restrict__ zW,
    const float* __restrict__ Wre, const float* __restrict__ bre,
    const float* __restrict__ Wde, const float* __restrict__ bde,
    const float* __restrict__ Wpe, const float* __restrict__ bpe,
    const float* __restrict__ Wrl, const float* __restrict__ Wdl,
    const float* __restrict__ Wpl, float* __restrict__ ws)
{
    __shared__ float sm[64*DIM];          // 8 KB
    __shared__ float E[64*33];            // emb+bias staging (padded)
    const int blk = blockIdx.x;
    const int tid = threadIdx.x;
    _Float16* AT = (_Float16*)(ws + OFF_ARENA);

    if (blk < NPAIR) {
        // ---- pair tables: sm rows 0..15 = R, 16..55 = D
        const float* Wlr = Wrl + blk*DIM*DIM;
        const float* Wld = Wdl + blk*DIM*DIM;
        for (int idx = tid; idx < (RB+DB)*DIM; idx += 256) {
            int k = idx >> 5, m = idx & 31;
            bool isR = k < RB;
            int kk = isR ? k : k - RB;
            E[k*33 + m] = isR ? (Wre[kk*DIM+m] + bre[m]) : (Wde[kk*DIM+m] + bde[m]);
        }
        __syncthreads();
        #pragma unroll
        for (int r = 0; r < 2; ++r) {
            if (tid < 224) {
                int k  = r*28 + (tid >> 3);
                int oq = (tid & 7) << 2;
                const float* Wl = (k < RB) ? Wlr : Wld;
                const float* ek = E + k*33;
                float4 a = make_float4(0.f,0.f,0.f,0.f);
                #pragma unroll 8
                for (int m = 0; m < DIM; ++m) {
                    float e = ek[m];
                    float4 w = *(const float4*)(Wl + m*DIM + oq);
                    a.x = fmaf(e, w.x, a.x); a.y = fmaf(e, w.y, a.y);
                    a.z = fmaf(e, w.z, a.z); a.w = fmaf(e, w.w, a.w);
                }
                *(float4*)(sm + k*DIM + oq) = a;
            }
        }
        __syncthreads();
        // SW units: V = R[r] + D[r], r = 2u+j (0..15)
        for (int idx = tid; idx < SW_U*128; idx += 256) {
            int u = idx >> 7, rem = idx & 127;
            int o = ((rem >> 3) << 1) | ((rem >> 2) & 1), j = rem & 3;
            int r = 2*u + j;
            AT[AR_SW + blk*(SW_U*128) + idx] = (_Float16)(sm[r*DIM+o] + sm[(RB+r)*DIM+o]);
        }
        // DW units: V = D[r] + R[15], r = 14+2u+j (14..39)
        for (int idx = tid; idx < DW_U*128; idx += 256) {
            int u = idx >> 7, rem = idx & 127;
            int o = ((rem >> 3) << 1) | ((rem >> 2) & 1), j = rem & 3;
            int r = 14 + 2*u + j;
            AT[AR_DW + blk*(DW_U*128) + idx] = (_Float16)(sm[(RB+r)*DIM+o] + sm[(RB-1)*DIM+o]);
        }
        // shells: RSH = R rows 12..15, DSH = D rows 14..17
        for (int idx = tid; idx < 128; idx += 256) {
            int o = ((idx >> 3) << 1) | ((idx >> 2) & 1), j = idx & 3;
            AT[AR_RSH + blk*128 + idx] = (_Float16)sm[(12 + j)*DIM + o];
            AT[AR_DSH + blk*128 + idx] = (_Float16)sm[(RB + 14 + j)*DIM + o];
        }
    } else if (blk < NTASK) {
        // ---- pos tables
        const int a3 = blk - NPAIR;
        const float* Wlp = Wpl + a3*DIM*DIM;
        for (int idx = tid; idx < PB*DIM; idx += 256) {
            int k = idx >> 5, m = idx & 31;
            E[k*33 + m] = Wpe[k*DIM+m] + bpe[m];
        }
        __syncthreads();
        #pragma unroll
        for (int r = 0; r < 2; ++r) {
            int k  = r*32 + (tid >> 3);
            int oq = (tid & 7) << 2;
            const float* ek = E + k*33;
            float4 a = make_float4(0.f,0.f,0.f,0.f);
            #pragma unroll 8
            for (int m = 0; m < DIM; ++m) {
                float e = ek[m];
                float4 w = *(const float4*)(Wlp + m*DIM + oq);
                a.x = fmaf(e, w.x, a.x); a.y = fmaf(e, w.y, a.y);
                a.z = fmaf(e, w.z, a.z); a.w = fmaf(e, w.w, a.w);
            }
            *(float4*)(sm + k*DIM + oq) = a;
        }
        __syncthreads();
        for (int idx = tid; idx < PW_U*128; idx += 256) {
            int u = idx >> 7, rem = idx & 127;
            int o = ((rem >> 3) << 1) | ((rem >> 2) & 1), j = rem & 3;
            AT[AR_PW + a3*(PW_U*128) + idx] = (_Float16)sm[(2*u + j)*DIM + o];
        }
    } else {
        // ---- G tile: 16 classes x 8 j-columns. 16 FMA per zW load.
        const int gb = blk - NTASK;
        const int cg = gb >> 2, jq = gb & 3;
        const int c0 = cg * 16;
        const int nc = (NCLS - c0 < 16) ? (NCLS - c0) : 16;
        for (int idx = tid; idx < 16*DIM; idx += 256)
            sm[idx] = (idx >> 5) < nc ? aa_emb[(c0 + (idx >> 5))*DIM + (idx & 31)] : 0.f;
        __syncthreads();
        const int h = tid & 127, jh = tid >> 7;
        for (int jj = 0; jj < 4; ++jj) {
            int j = jq*8 + jh*4 + jj;
            float acc[16];
            #pragma unroll
            for (int cc = 0; cc < 16; ++cc) acc[cc] = 0.f;
            for (int i = 0; i < DIM; ++i) {
                float w = zW[(size_t)(i*DIM + j)*EDGE + h];
                #pragma unroll
                for (int cc = 0; cc < 16; ++cc)
                    acc[cc] = fmaf(sm[cc*DIM + i], w, acc[cc]);
            }
            for (int cc = 0; cc < nc; ++cc)
                ws[OFF_G + (size_t)(c0+cc)*DIM*EDGE + j*EDGE + h] = acc[cc];
        }
    }
}

// ---------------------------------------------------------------------------
// 3-bin truncated gaussian softmax, 2-exp relative form: weights proportional
// to {2^(C(2d+1)), 1, 2^(C(1-2d))}, d = u - k0 (center-bin offset).
// Exponent clamp at +80 replaces max-subtraction for clamped-edge bins
// (t*inv -> m exactly; no inf/NaN: exp2(80)=1.2e24, inv ~ 8e-25 normal).
// ---------------------------------------------------------------------------
__device__ __forceinline__ void probs3(float u, int k0, float m, float* pr)
{
    const float C = -18.03368928f;        // -12.5 * log2(e)
    float dd = u - (float)k0;
    float r0 = fminf(C * (2.f*dd + 1.f), 80.f);
    float r2 = fminf(C * (1.f - 2.f*dd), 80.f);
    float t0 = __builtin_exp2f(r0);
    float t2 = __builtin_exp2f(r2);
    float inv = m / (t0 + 1.f + t2);
    pr[0] = t0 * inv; pr[1] = inv; pr[2] = t2 * inv;
}

// rows b..b+2 within the 4-row unit starting at row 2*(b>>1):
// b even -> [w0,w1,w2,0]; b odd -> [0,w0,w1,w2]. Packed as 2x f16-pairs.
__device__ __forceinline__ void packW(const float* w, int b,
                                      unsigned int& wp0, unsigned int& wp1)
{
    if (b & 1) { wp0 = pack2(0.f, w[0]);  wp1 = pack2(w[1], w[2]); }
    else       { wp0 = pack2(w[0], w[1]); wp1 = pack2(w[2], 0.f); }
}

// ---------------------------------------------------------------------------
// struct_fd: one block (256 thr) per pid = blockIdx.x. Natural order keeps
// G L2-hot: a p-stripe's 128 blocks touch <=21 distinct 16KB G tiles.
// Phase 1: 1 task/thread -> job {unit elem offset, wp0, wp1}; kf==15 pairs
//   emit a second job (ballot-compacted); pad to x16 with zero jobs.
// Phase 2: lane l: job-group l>>4, dim-pair l&15; per 16 jobs/wave-iter:
//   1 ds_read_b128 + 1 global dwordx4 + 4 fdot2.
// Phase 3 (fused): fd in LDS; Z[h] = zb[h] + sum_j fd[j]*G[cls][j][h].
// ---------------------------------------------------------------------------
__global__ __launch_bounds__(256) void struct_fd(
    const int*   __restrict__ aat1,
    const float* __restrict__ pos_a, const float* __restrict__ mask_a,
    const float* __restrict__ pos_b, const float* __restrict__ mask_b,
    const float* __restrict__ rots,  const float* __restrict__ trans,
    const float* __restrict__ brl,   const float* __restrict__ bdl,
    const float* __restrict__ bpl,   const float* __restrict__ zb,
    const float* __restrict__ ws,    float* __restrict__ out)
{
    const int pid = blockIdx.x;
    const int p = pid >> 7, q = pid & 127;
    __shared__ uint4 jobs[MAXJOBS + 16];
    __shared__ int   extCnt[4];
    __shared__ int   extTot;
    __shared__ float sacc[16][DIM];
    __shared__ float fdv[DIM];
    __shared__ float zpart[2][EDGE];
    const int t = threadIdx.x;
    const int lane = t & 63;
    const int wid  = t >> 6;

    bool  flag = false;
    uint4 extraJ = make_uint4(0,0,0,0);

    // ---- Phase 1 ----
    if (t < NTASK) {
        uint4 J;
        if (t < NPAIR) {
            int i = t / A_, j = t % A_;
            float ax = pos_a[(p*A_+i)*3+0], ay = pos_a[(p*A_+i)*3+1], az = pos_a[(p*A_+i)*3+2];
            float bx = pos_b[(q*A_+j)*3+0], by = pos_b[(q*A_+j)*3+1], bz = pos_b[(q*A_+j)*3+2];
            float dx = bx-ax, dy = by-ay, dz = bz-az;
            float d  = sqrtf(dx*dx + dy*dy + dz*dz);
            float m  = mask_a[p*A_+i] * mask_b[q*A_+j];
            float u  = (d - 2.625f) * 0.8f;      // shared off0/s for rough & dist
            int  kf  = (int)rintf(u);
            float w[3]; unsigned int off, wp0, wp1; int b;
            if (kf <= RB-2) {                    // merged rough+dist, rows 0..15
                int k0 = max(kf, 1);
                probs3(u, k0, m, w);
                b = k0 - 1;
                off = AR_SW + t*(SW_U*128) + (b>>1)*128;
            } else if (kf == RB-1) {             // shell: two exact jobs
                probs3(u, RB-2, m, w);           // R rows 13..15 in unit rows 12..15
                b = 13;
                off = AR_RSH + t*128;
                float we[3];
                probs3(u, RB-1, m, we);          // D rows 14..16 in unit rows 14..17
                unsigned int e0, e1;
                packW(we, 14, e0, e1);
                extraJ = make_uint4(AR_DSH + t*128, e0, e1, 0);
                flag = true;
            } else {                             // far: dist + folded rough edge
                int kd = min(kf, DB-2);
                probs3(u, kd, m, w);
                b = kd - 1;                      // 15..37 -> unit (b>>1)-7
                off = AR_DW + t*(DW_U*128) + ((b>>1) - 7)*128;
            }
            packW(w, b, wp0, wp1);
            J = make_uint4(off, wp0, wp1, 0);
        } else {
            int idx = t - NPAIR;
            int a = idx / 3, c = idx % 3;
            float lv = 0.f;
            #pragma unroll
            for (int jr = 0; jr < 3; ++jr)
                lv = fmaf(rots[p*9 + jr*3 + c],
                          pos_b[(q*A_+a)*3 + jr] - trans[p*3 + jr], lv);
            float m = mask_b[p*A_+a] * mask_b[q*A_+a];
            float u = (lv + 32.f + 0.5f*(64.f/62.f)) * 0.96875f;   // 1/s = 62/64
            int kp = min(max((int)rintf(u), 1), PB-2);
            float w[3]; probs3(u, kp, m, w);
            int b = kp - 1;
            unsigned int wp0, wp1;
            packW(w, b, wp0, wp1);
            J = make_uint4(AR_PW + idx*(PW_U*128) + (b>>1)*128, wp0, wp1, 0);
        }
        jobs[t] = J;
    }
    unsigned long long bal = __ballot(flag);
    if (lane == 0) extCnt[wid] = __popcll(bal);
    int myPos = __popcll(bal & ((1ull << lane) - 1ull));
    __syncthreads();
    if (t == 0) {
        int s = NTASK;
        #pragma unroll
        for (int g = 0; g < 4; ++g) { int c = extCnt[g]; extCnt[g] = s; s += c; }
        extTot = s;
    }
    __syncthreads();
    if (flag) jobs[extCnt[wid] + myPos] = extraJ;
    if (t < 16) {                       // zero-pad to multiple of 16
        int idx = extTot + t;
        if (idx < ((extTot + 15) & ~15)) jobs[idx] = make_uint4(0,0,0,0);
    }
    __syncthreads();

    // ---- Phase 2 ----
    const int g16 = t >> 4;             // job slot within 16-batch
    const int o2  = t & 15;             // dim pair
    const unsigned short* Ta = (const unsigned short*)(ws + OFF_ARENA);
    const int nj16 = (extTot + 15) & ~15;
    float accA = 0.f, accB = 0.f;
    #pragma unroll 2
    for (int itb = 0; itb < nj16; itb += 16) {
        uint4 J = jobs[itb + g16];
        uint4 v = *(const uint4*)(Ta + J.x + (o2 << 3));
        accA = fdot2f(v.x, J.y, accA);
        accA = fdot2f(v.y, J.z, accA);
        accB = fdot2f(v.z, J.y, accB);
        accB = fdot2f(v.w, J.z, accB);
    }
    sacc[g16][o2*2]   = accA;
    sacc[g16][o2*2+1] = accB;
    __syncthreads();
    if (t < DIM) {
        float v = brl[t] + bdl[t] + bpl[t];
        #pragma unroll
        for (int g = 0; g < 16; ++g) v += sacc[g][t];
        fdv[t] = v;
    }
    __syncthreads();

    // ---- Phase 3 (fused): Z[h] = zb[h] + sum_j fdv[j]*G[cls][j][h] ----
    const int cls = aat1[p]*21 + aat1[q];
    const int h  = t & 127, jh = t >> 7;
    const float* Gp = ws + OFF_G + (size_t)cls*DIM*EDGE + jh*(16*EDGE) + h;
    float zp = 0.f;
    #pragma unroll
    for (int jj = 0; jj < 16; ++jj)
        zp = fmaf(fdv[jh*16 + jj], Gp[jj*EDGE], zp);
    zpart[jh][h] = zp;
    __syncthreads();
    if (t < EDGE)
        out[(size_t)pid*EDGE + t] = zpart[0][t] + zpart[1][t] + zb[t];
}

extern "C" void kernel_launch(void* const* d_in, const int* in_sizes, int n_in,
                              void* d_out, int out_size, void* d_ws, size_t ws_size,
                              hipStream_t stream)
{
    const int*   aat1   = (const int*)  d_in[0];
    const float* pos_a  = (const float*)d_in[2];
    const float* mask_a = (const float*)d_in[3];
    const float* pos_b  = (const float*)d_in[4];
    const float* mask_b = (const float*)d_in[5];
    const float* rots   = (const float*)d_in[6];
    const float* trans  = (const float*)d_in[7];
    const float* aa_emb = (const float*)d_in[8];
    const float* Wre    = (const float*)d_in[9];
    const float* bre    = (const float*)d_in[10];
    const float* Wde    = (const float*)d_in[11];
    const float* bde    = (const float*)d_in[12];
    const float* Wpe    = (const float*)d_in[13];
    const float* bpe    = (const float*)d_in[14];
    const float* Wrl    = (const float*)d_in[15];
    const float* brl    = (const float*)d_in[16];
    const float* Wdl    = (const float*)d_in[17];
    const float* bdl    = (const float*)d_in[18];
    const float* Wpl    = (const float*)d_in[19];
    const float* bpl    = (const float*)d_in[20];
    const float* zW     = (const float*)d_in[21];
    const float* zb     = (const float*)d_in[22];
    float* ws   = (float*)d_ws;
    float* outp = (float*)d_out;

    hipLaunchKernelGGL(preproc, dim3(NPRE), dim3(256), 0, stream,
                       aa_emb, zW,
                       Wre, bre, Wde, bde, Wpe, bpe, Wrl, Wdl, Wpl, ws);
    hipLaunchKernelGGL(struct_fd, dim3(NPID), dim3(256), 0, stream,
                       aat1, pos_a, mask_a, pos_b, mask_b, rots, trans,
                       brl, bdl, bpl, zb, ws, outp);
}

// Round 11
// 78.360 us; speedup vs baseline: 1.1379x; 1.1379x over previous
//
#include <hip/hip_runtime.h>
#include <hip/hip_bf16.h>
#include <math.h>

#define S_   128
#define A_   14
#define DIM  32
#define EDGE 128
#define NPAIR 196         // A*A
#define NPOS  42          // A*3
#define NTASK 238         // NPAIR + NPOS
#define RB 16
#define DB 40
#define PB 64
#define NCLS 441
#define NPID (S_*S_)

// ---- f16 arena: 4-row units. Unit = [o2(16)][d(2)][j(4)] = 128 f16 = 256 B.
// Unit u covers rows rlo..rlo+3; element (o2,d,j) = dim 2*o2+d, row rlo+j.
#define SW_U 7            // rows 2u..2u+3, u=0..6  (R+D rows 0..15)
#define DW_U 12           // rows 14+2u..17+2u      (D rows 14..39, + R[15])
#define PW_U 31           // rows 2u..2u+3          (P rows 0..63)
#define AR_SW   0
#define AR_DW   (AR_SW + NPAIR*SW_U*128)
#define AR_RSH  (AR_DW + NPAIR*DW_U*128)    // R rows 12..15, 1 unit/task
#define AR_DSH  (AR_RSH + NPAIR*128)        // D rows 14..17, 1 unit/task
#define AR_PW   (AR_DSH + NPAIR*128)
#define AR_TOT  (AR_PW + NPOS*PW_U*128)     // 693504 f16 = 1.39 MB

// ---- ws layout (float units)
#define OFF_G      0
#define OFF_ARENA  (OFF_G + NCLS*DIM*EDGE)     // f16 arena

#define MAXJOBS (NTASK + NPAIR)
#define NGBLK   224        // 56 class-groups (8 cls) x 4 j-quarters
#define NPRE    (NTASK + NGBLK)

typedef _Float16 h2 __attribute__((ext_vector_type(2)));

#if defined(__has_builtin)
#if __has_builtin(__builtin_amdgcn_fdot2)
#define HAVE_FDOT2 1
#endif
#endif

__device__ __forceinline__ float fdot2f(unsigned int a, unsigned int b, float c) {
    h2 ha = __builtin_bit_cast(h2, a), hb = __builtin_bit_cast(h2, b);
#ifdef HAVE_FDOT2
    return __builtin_amdgcn_fdot2(ha, hb, c, false);
#else
    return c + (float)ha[0]*(float)hb[0] + (float)ha[1]*(float)hb[1];
#endif
}

__device__ __forceinline__ unsigned int pack2(float lo, float hi) {
    _Float16 l = (_Float16)lo, h = (_Float16)hi;
    unsigned short lu = __builtin_bit_cast(unsigned short, l);
    unsigned short hu = __builtin_bit_cast(unsigned short, h);
    return (unsigned int)lu | ((unsigned int)hu << 16);
}

// ---------------------------------------------------------------------------
// Fused preprocessing: blocks 0..195 pair tables, 196..237 pos tables,
// 238..461 G (8-class x 8-j tiles).
// G path: aa_emb read DIRECTLY from global with block-uniform addresses ->
// scalar-pipe s_loads (R10 post-mortem: the old LDS-staged version issued
// 2048 ds_read_b32/thread = ~20us of LDS-pipe serialization per CU).
// Pair/pos compute: stage E[k][m] = emb+bias in LDS (padded 33), then
// thread=(k, o-quad) does float4 Wl-row loads + 4 FMA per m (2 k-rounds).
// ---------------------------------------------------------------------------
__global__ __launch_bounds__(256) void preproc(
    const float* __restrict__ aa_emb, const float* __restrict__ zW,
    const float* __restrict__ Wre, const float* __restrict__ bre,
    const float* __restrict__ Wde, const float* __restrict__ bde,
    const float* __restrict__ Wpe, const float* __restrict__ bpe,
    const float* __restrict__ Wrl, const float* __restrict__ Wdl,
    const float* __restrict__ Wpl, float* __restrict__ ws)
{
    __shared__ float sm[64*DIM];          // 8 KB
    __shared__ float E[64*33];            // emb+bias staging (padded)
    const int blk = blockIdx.x;
    const int tid = threadIdx.x;
    _Float16* AT = (_Float16*)(ws + OFF_ARENA);

    if (blk < NPAIR) {
        // ---- pair tables: sm rows 0..15 = R, 16..55 = D
        const float* Wlr = Wrl + blk*DIM*DIM;
        const float* Wld = Wdl + blk*DIM*DIM;
        for (int idx = tid; idx < (RB+DB)*DIM; idx += 256) {
            int k = idx >> 5, m = idx & 31;
            bool isR = k < RB;
            int kk = isR ? k : k - RB;
            E[k*33 + m] = isR ? (Wre[kk*DIM+m] + bre[m]) : (Wde[kk*DIM+m] + bde[m]);
        }
        __syncthreads();
        #pragma unroll
        for (int r = 0; r < 2; ++r) {
            if (tid < 224) {
                int k  = r*28 + (tid >> 3);
                int oq = (tid & 7) << 2;
                const float* Wl = (k < RB) ? Wlr : Wld;
                const float* ek = E + k*33;
                float4 a = make_float4(0.f,0.f,0.f,0.f);
                #pragma unroll 8
                for (int m = 0; m < DIM; ++m) {
                    float e = ek[m];
                    float4 w = *(const float4*)(Wl + m*DIM + oq);
                    a.x = fmaf(e, w.x, a.x); a.y = fmaf(e, w.y, a.y);
                    a.z = fmaf(e, w.z, a.z); a.w = fmaf(e, w.w, a.w);
                }
                *(float4*)(sm + k*DIM + oq) = a;
            }
        }
        __syncthreads();
        // SW units: V = R[r] + D[r], r = 2u+j (0..15)
        for (int idx = tid; idx < SW_U*128; idx += 256) {
            int u = idx >> 7, rem = idx & 127;
            int o = ((rem >> 3) << 1) | ((rem >> 2) & 1), j = rem & 3;
            int r = 2*u + j;
            AT[AR_SW + blk*(SW_U*128) + idx] = (_Float16)(sm[r*DIM+o] + sm[(RB+r)*DIM+o]);
        }
        // DW units: V = D[r] + R[15], r = 14+2u+j (14..39)
        for (int idx = tid; idx < DW_U*128; idx += 256) {
            int u = idx >> 7, rem = idx & 127;
            int o = ((rem >> 3) << 1) | ((rem >> 2) & 1), j = rem & 3;
            int r = 14 + 2*u + j;
            AT[AR_DW + blk*(DW_U*128) + idx] = (_Float16)(sm[(RB+r)*DIM+o] + sm[(RB-1)*DIM+o]);
        }
        // shells: RSH = R rows 12..15, DSH = D rows 14..17
        for (int idx = tid; idx < 128; idx += 256) {
            int o = ((idx >> 3) << 1) | ((idx >> 2) & 1), j = idx & 3;
            AT[AR_RSH + blk*128 + idx] = (_Float16)sm[(12 + j)*DIM + o];
            AT[AR_DSH + blk*128 + idx] = (_Float16)sm[(RB + 14 + j)*DIM + o];
        }
    } else if (blk < NTASK) {
        // ---- pos tables
        const int a3 = blk - NPAIR;
        const float* Wlp = Wpl + a3*DIM*DIM;
        for (int idx = tid; idx < PB*DIM; idx += 256) {
            int k = idx >> 5, m = idx & 31;
            E[k*33 + m] = Wpe[k*DIM+m] + bpe[m];
        }
        __syncthreads();
        #pragma unroll
        for (int r = 0; r < 2; ++r) {
            int k  = r*32 + (tid >> 3);
            int oq = (tid & 7) << 2;
            const float* ek = E + k*33;
            float4 a = make_float4(0.f,0.f,0.f,0.f);
            #pragma unroll 8
            for (int m = 0; m < DIM; ++m) {
                float e = ek[m];
                float4 w = *(const float4*)(Wlp + m*DIM + oq);
                a.x = fmaf(e, w.x, a.x); a.y = fmaf(e, w.y, a.y);
                a.z = fmaf(e, w.z, a.z); a.w = fmaf(e, w.w, a.w);
            }
            *(float4*)(sm + k*DIM + oq) = a;
        }
        __syncthreads();
        for (int idx = tid; idx < PW_U*128; idx += 256) {
            int u = idx >> 7, rem = idx & 127;
            int o = ((rem >> 3) << 1) | ((rem >> 2) & 1), j = rem & 3;
            AT[AR_PW + a3*(PW_U*128) + idx] = (_Float16)sm[(2*u + j)*DIM + o];
        }
    } else {
        // ---- G tile: 8 classes x 8 j-columns; aa_emb via uniform s_loads.
        const int gb = blk - NTASK;        // 0..223
        const int cg = gb >> 2, jq = gb & 3;
        const int c0 = cg * 8;
        const int nc = (NCLS - c0 < 8) ? (NCLS - c0) : 8;
        const int h = tid & 127, jh = tid >> 7;
        #pragma unroll
        for (int jj = 0; jj < 4; ++jj) {
            int j = jq*8 + jh*4 + jj;
            float acc[8];
            #pragma unroll
            for (int cc = 0; cc < 8; ++cc) acc[cc] = 0.f;
            #pragma unroll 4
            for (int i = 0; i < DIM; ++i) {
                float w = zW[(size_t)(i*DIM + j)*EDGE + h];
                #pragma unroll
                for (int cc = 0; cc < 8; ++cc) {
                    int cI = c0 + cc; if (cI > NCLS-1) cI = NCLS-1;
                    acc[cc] = fmaf(aa_emb[cI*DIM + i], w, acc[cc]);
                }
            }
            for (int cc = 0; cc < nc; ++cc)
                ws[OFF_G + (size_t)(c0+cc)*DIM*EDGE + j*EDGE + h] = acc[cc];
        }
    }
}

// ---------------------------------------------------------------------------
// 3-bin truncated gaussian softmax, 2-exp relative form: weights proportional
// to {2^(C(2d+1)), 1, 2^(C(1-2d))}, d = u - k0 (center-bin offset).
// Exponent clamp at +80 replaces max-subtraction for clamped-edge bins
// (t*inv -> m exactly; no inf/NaN: exp2(80)=1.2e24, inv ~ 8e-25 normal).
// ---------------------------------------------------------------------------
__device__ __forceinline__ void probs3(float u, int k0, float m, float* pr)
{
    const float C = -18.03368928f;        // -12.5 * log2(e)
    float dd = u - (float)k0;
    float r0 = fminf(C * (2.f*dd + 1.f), 80.f);
    float r2 = fminf(C * (1.f - 2.f*dd), 80.f);
    float t0 = __builtin_exp2f(r0);
    float t2 = __builtin_exp2f(r2);
    float inv = m / (t0 + 1.f + t2);
    pr[0] = t0 * inv; pr[1] = inv; pr[2] = t2 * inv;
}

// rows b..b+2 within the 4-row unit starting at row 2*(b>>1):
// b even -> [w0,w1,w2,0]; b odd -> [0,w0,w1,w2]. Packed as 2x f16-pairs.
__device__ __forceinline__ void packW(const float* w, int b,
                                      unsigned int& wp0, unsigned int& wp1)
{
    if (b & 1) { wp0 = pack2(0.f, w[0]);  wp1 = pack2(w[1], w[2]); }
    else       { wp0 = pack2(w[0], w[1]); wp1 = pack2(w[2], 0.f); }
}

// ---------------------------------------------------------------------------
// struct_fd: one block (256 thr) per pid = blockIdx.x. Natural order keeps
// G reasonably L2-hot (blocks in flight span ~12 p-rows -> ~4 MB/XCD).
// Phase 1: 1 task/thread -> job {unit elem offset, wp0, wp1}; kf==15 pairs
//   emit a second job (ballot-compacted); pad to x16 with zero jobs.
// Phase 2: lane l: job-group l>>4, dim-pair l&15; per 16 jobs/wave-iter:
//   1 ds_read_b128 + 1 global dwordx4 + 4 fdot2.
// Phase 3 (fused): fd in LDS; Z[h] = zb[h] + sum_j fd[j]*G[cls][j][h].
// ---------------------------------------------------------------------------
__global__ __launch_bounds__(256) void struct_fd(
    const int*   __restrict__ aat1,
    const float* __restrict__ pos_a, const float* __restrict__ mask_a,
    const float* __restrict__ pos_b, const float* __restrict__ mask_b,
    const float* __restrict__ rots,  const float* __restrict__ trans,
    const float* __restrict__ brl,   const float* __restrict__ bdl,
    const float* __restrict__ bpl,   const float* __restrict__ zb,
    const float* __restrict__ ws,    float* __restrict__ out)
{
    const int pid = blockIdx.x;
    const int p = pid >> 7, q = pid & 127;
    __shared__ uint4 jobs[MAXJOBS + 16];
    __shared__ int   extCnt[4];
    __shared__ int   extTot;
    __shared__ float sacc[16][DIM];
    __shared__ float fdv[DIM];
    __shared__ float zpart[2][EDGE];
    const int t = threadIdx.x;
    const int lane = t & 63;
    const int wid  = t >> 6;

    bool  flag = false;
    uint4 extraJ = make_uint4(0,0,0,0);

    // ---- Phase 1 ----
    if (t < NTASK) {
        uint4 J;
        if (t < NPAIR) {
            int i = t / A_, j = t % A_;
            float ax = pos_a[(p*A_+i)*3+0], ay = pos_a[(p*A_+i)*3+1], az = pos_a[(p*A_+i)*3+2];
            float bx = pos_b[(q*A_+j)*3+0], by = pos_b[(q*A_+j)*3+1], bz = pos_b[(q*A_+j)*3+2];
            float dx = bx-ax, dy = by-ay, dz = bz-az;
            float d  = sqrtf(dx*dx + dy*dy + dz*dz);
            float m  = mask_a[p*A_+i] * mask_b[q*A_+j];
            float u  = (d - 2.625f) * 0.8f;      // shared off0/s for rough & dist
            int  kf  = (int)rintf(u);
            float w[3]; unsigned int off, wp0, wp1; int b;
            if (kf <= RB-2) {                    // merged rough+dist, rows 0..15
                int k0 = max(kf, 1);
                probs3(u, k0, m, w);
                b = k0 - 1;
                off = AR_SW + t*(SW_U*128) + (b>>1)*128;
            } else if (kf == RB-1) {             // shell: two exact jobs
                probs3(u, RB-2, m, w);           // R rows 13..15 in unit rows 12..15
                b = 13;
                off = AR_RSH + t*128;
                float we[3];
                probs3(u, RB-1, m, we);          // D rows 14..16 in unit rows 14..17
                unsigned int e0, e1;
                packW(we, 14, e0, e1);
                extraJ = make_uint4(AR_DSH + t*128, e0, e1, 0);
                flag = true;
            } else {                             // far: dist + folded rough edge
                int kd = min(kf, DB-2);
                probs3(u, kd, m, w);
                b = kd - 1;                      // 15..37 -> unit (b>>1)-7
                off = AR_DW + t*(DW_U*128) + ((b>>1) - 7)*128;
            }
            packW(w, b, wp0, wp1);
            J = make_uint4(off, wp0, wp1, 0);
        } else {
            int idx = t - NPAIR;
            int a = idx / 3, c = idx % 3;
            float lv = 0.f;
            #pragma unroll
            for (int jr = 0; jr < 3; ++jr)
                lv = fmaf(rots[p*9 + jr*3 + c],
                          pos_b[(q*A_+a)*3 + jr] - trans[p*3 + jr], lv);
            float m = mask_b[p*A_+a] * mask_b[q*A_+a];
            float u = (lv + 32.f + 0.5f*(64.f/62.f)) * 0.96875f;   // 1/s = 62/64
            int kp = min(max((int)rintf(u), 1), PB-2);
            float w[3]; probs3(u, kp, m, w);
            int b = kp - 1;
            unsigned int wp0, wp1;
            packW(w, b, wp0, wp1);
            J = make_uint4(AR_PW + idx*(PW_U*128) + (b>>1)*128, wp0, wp1, 0);
        }
        jobs[t] = J;
    }
    unsigned long long bal = __ballot(flag);
    if (lane == 0) extCnt[wid] = __popcll(bal);
    int myPos = __popcll(bal & ((1ull << lane) - 1ull));
    __syncthreads();
    if (t == 0) {
        int s = NTASK;
        #pragma unroll
        for (int g = 0; g < 4; ++g) { int c = extCnt[g]; extCnt[g] = s; s += c; }
        extTot = s;
    }
    __syncthreads();
    if (flag) jobs[extCnt[wid] + myPos] = extraJ;
    if (t < 16) {                       // zero-pad to multiple of 16
        int idx = extTot + t;
        if (idx < ((extTot + 15) & ~15)) jobs[idx] = make_uint4(0,0,0,0);
    }
    __syncthreads();

    // ---- Phase 2 ----
    const int g16 = t >> 4;             // job slot within 16-batch
    const int o2  = t & 15;             // dim pair
    const unsigned short* Ta = (const unsigned short*)(ws + OFF_ARENA);
    const int nj16 = (extTot + 15) & ~15;
    float accA = 0.f, accB = 0.f;
    #pragma unroll 2
    for (int itb = 0; itb < nj16; itb += 16) {
        uint4 J = jobs[itb + g16];
        uint4 v = *(const uint4*)(Ta + J.x + (o2 << 3));
        accA = fdot2f(v.x, J.y, accA);
        accA = fdot2f(v.y, J.z, accA);
        accB = fdot2f(v.z, J.y, accB);
        accB = fdot2f(v.w, J.z, accB);
    }
    sacc[g16][o2*2]   = accA;
    sacc[g16][o2*2+1] = accB;
    __syncthreads();
    if (t < DIM) {
        float v = brl[t] + bdl[t] + bpl[t];
        #pragma unroll
        for (int g = 0; g < 16; ++g) v += sacc[g][t];
        fdv[t] = v;
    }
    __syncthreads();

    // ---- Phase 3 (fused): Z[h] = zb[h] + sum_j fdv[j]*G[cls][j][h] ----
    const int cls = aat1[p]*21 + aat1[q];
    const int h  = t & 127, jh = t >> 7;
    const float* Gp = ws + OFF_G + (size_t)cls*DIM*EDGE + jh*(16*EDGE) + h;
    float zp = 0.f;
    #pragma unroll
    for (int jj = 0; jj < 16; ++jj)
        zp = fmaf(fdv[jh*16 + jj], Gp[jj*EDGE], zp);
    zpart[jh][h] = zp;
    __syncthreads();
    if (t < EDGE)
        out[(size_t)pid*EDGE + t] = zpart[0][t] + zpart[1][t] + zb[t];
}

extern "C" void kernel_launch(void* const* d_in, const int* in_sizes, int n_in,
                              void* d_out, int out_size, void* d_ws, size_t ws_size,
                              hipStream_t stream)
{
    const int*   aat1   = (const int*)  d_in[0];
    const float* pos_a  = (const float*)d_in[2];
    const float* mask_a = (const float*)d_in[3];
    const float* pos_b  = (const float*)d_in[4];
    const float* mask_b = (const float*)d_in[5];
    const float* rots   = (const float*)d_in[6];
    const float* trans  = (const float*)d_in[7];
    const float* aa_emb = (const float*)d_in[8];
    const float* Wre    = (const float*)d_in[9];
    const float* bre    = (const float*)d_in[10];
    const float* Wde    = (const float*)d_in[11];
    const float* bde    = (const float*)d_in[12];
    const float* Wpe    = (const float*)d_in[13];
    const float* bpe    = (const float*)d_in[14];
    const float* Wrl    = (const float*)d_in[15];
    const float* brl    = (const float*)d_in[16];
    const float* Wdl    = (const float*)d_in[17];
    const float* bdl    = (const float*)d_in[18];
    const float* Wpl    = (const float*)d_in[19];
    const float* bpl    = (const float*)d_in[20];
    const float* zW     = (const float*)d_in[21];
    const float* zb     = (const float*)d_in[22];
    float* ws   = (float*)d_ws;
    float* outp = (float*)d_out;

    hipLaunchKernelGGL(preproc, dim3(NPRE), dim3(256), 0, stream,
                       aa_emb, zW,
                       Wre, bre, Wde, bde, Wpe, bpe, Wrl, Wdl, Wpl, ws);
    hipLaunchKernelGGL(struct_fd, dim3(NPID), dim3(256), 0, stream,
                       aat1, pos_a, mask_a, pos_b, mask_b, rots, trans,
                       brl, bdl, bpl, zb, ws, outp);
}

// Round 12
// 75.164 us; speedup vs baseline: 1.1863x; 1.0425x over previous
//
#include <hip/hip_runtime.h>
#include <hip/hip_bf16.h>
#include <math.h>

#define S_   128
#define A_   14
#define DIM  32
#define EDGE 128
#define NPAIR 196         // A*A
#define NPOS  42          // A*3
#define NTASK 238         // NPAIR + NPOS
#define RB 16
#define DB 40
#define PB 64
#define NCLS 441
#define NPID (S_*S_)

// ---- f16 arena: 4-row units. Unit = [o2(16)][d(2)][j(4)] = 128 f16 = 256 B.
// Unit u covers rows rlo..rlo+3; element (o2,d,j) = dim 2*o2+d, row rlo+j.
#define SW_U 7            // rows 2u..2u+3, u=0..6  (R+D rows 0..15)
#define DW_U 12           // rows 14+2u..17+2u      (D rows 14..39, + R[15])
#define PW_U 31           // rows 2u..2u+3          (P rows 0..63)
#define AR_SW   0
#define AR_DW   (AR_SW + NPAIR*SW_U*128)
#define AR_RSH  (AR_DW + NPAIR*DW_U*128)    // R rows 12..15, 1 unit/task
#define AR_DSH  (AR_RSH + NPAIR*128)        // D rows 14..17, 1 unit/task
#define AR_PW   (AR_DSH + NPAIR*128)
#define AR_TOT  (AR_PW + NPOS*PW_U*128)     // 693504 f16 = 1.39 MB

// byte-offset versions (jobs carry byte offsets)
#define ARB_SW  (AR_SW*2)
#define ARB_DW  (AR_DW*2)
#define ARB_RSH (AR_RSH*2)
#define ARB_DSH (AR_DSH*2)
#define ARB_PW  (AR_PW*2)

// ---- ws layout (float units)
#define OFF_G      0
#define OFF_ARENA  (OFF_G + NCLS*DIM*EDGE)     // f16 arena

#define MAXJOBS (NTASK + NPAIR)
#define NGBLK   224        // 56 class-groups (8 cls) x 4 j-quarters
#define NPRE    (NTASK + NGBLK)

typedef _Float16 h2 __attribute__((ext_vector_type(2)));

#if defined(__has_builtin)
#if __has_builtin(__builtin_amdgcn_fdot2)
#define HAVE_FDOT2 1
#endif
#endif

__device__ __forceinline__ float fdot2f(unsigned int a, unsigned int b, float c) {
    h2 ha = __builtin_bit_cast(h2, a), hb = __builtin_bit_cast(h2, b);
#ifdef HAVE_FDOT2
    return __builtin_amdgcn_fdot2(ha, hb, c, false);
#else
    return c + (float)ha[0]*(float)hb[0] + (float)ha[1]*(float)hb[1];
#endif
}

__device__ __forceinline__ unsigned int pack2(float lo, float hi) {
    _Float16 l = (_Float16)lo, h = (_Float16)hi;
    unsigned short lu = __builtin_bit_cast(unsigned short, l);
    unsigned short hu = __builtin_bit_cast(unsigned short, h);
    return (unsigned int)lu | ((unsigned int)hu << 16);
}

// ---------------------------------------------------------------------------
// Fused preprocessing: blocks 0..195 pair tables, 196..237 pos tables,
// 238..461 G (8-class x 8-j tiles, aa_emb via uniform s_loads).
// Pair/pos compute: stage E[k][m] = emb+bias in LDS (padded 33), then
// thread=(k, o-quad) does float4 Wl-row loads + 4 FMA per m (2 k-rounds).
// ---------------------------------------------------------------------------
__global__ __launch_bounds__(256) void preproc(
    const float* __restrict__ aa_emb, const float* __restrict__ zW,
    const float* __restrict__ Wre, const float* __restrict__ bre,
    const float* __restrict__ Wde, const float* __restrict__ bde,
    const float* __restrict__ Wpe, const float* __restrict__ bpe,
    const float* __restrict__ Wrl, const float* __restrict__ Wdl,
    const float* __restrict__ Wpl, float* __restrict__ ws)
{
    __shared__ float sm[64*DIM];          // 8 KB
    __shared__ float E[64*33];            // emb+bias staging (padded)
    const int blk = blockIdx.x;
    const int tid = threadIdx.x;
    _Float16* AT = (_Float16*)(ws + OFF_ARENA);

    if (blk < NPAIR) {
        // ---- pair tables: sm rows 0..15 = R, 16..55 = D
        const float* Wlr = Wrl + blk*DIM*DIM;
        const float* Wld = Wdl + blk*DIM*DIM;
        for (int idx = tid; idx < (RB+DB)*DIM; idx += 256) {
            int k = idx >> 5, m = idx & 31;
            bool isR = k < RB;
            int kk = isR ? k : k - RB;
            E[k*33 + m] = isR ? (Wre[kk*DIM+m] + bre[m]) : (Wde[kk*DIM+m] + bde[m]);
        }
        __syncthreads();
        #pragma unroll
        for (int r = 0; r < 2; ++r) {
            if (tid < 224) {
                int k  = r*28 + (tid >> 3);
                int oq = (tid & 7) << 2;
                const float* Wl = (k < RB) ? Wlr : Wld;
                const float* ek = E + k*33;
                float4 a = make_float4(0.f,0.f,0.f,0.f);
                #pragma unroll 8
                for (int m = 0; m < DIM; ++m) {
                    float e = ek[m];
                    float4 w = *(const float4*)(Wl + m*DIM + oq);
                    a.x = fmaf(e, w.x, a.x); a.y = fmaf(e, w.y, a.y);
                    a.z = fmaf(e, w.z, a.z); a.w = fmaf(e, w.w, a.w);
                }
                *(float4*)(sm + k*DIM + oq) = a;
            }
        }
        __syncthreads();
        // SW units: V = R[r] + D[r], r = 2u+j (0..15)
        for (int idx = tid; idx < SW_U*128; idx += 256) {
            int u = idx >> 7, rem = idx & 127;
            int o = ((rem >> 3) << 1) | ((rem >> 2) & 1), j = rem & 3;
            int r = 2*u + j;
            AT[AR_SW + blk*(SW_U*128) + idx] = (_Float16)(sm[r*DIM+o] + sm[(RB+r)*DIM+o]);
        }
        // DW units: V = D[r] + R[15], r = 14+2u+j (14..39)
        for (int idx = tid; idx < DW_U*128; idx += 256) {
            int u = idx >> 7, rem = idx & 127;
            int o = ((rem >> 3) << 1) | ((rem >> 2) & 1), j = rem & 3;
            int r = 14 + 2*u + j;
            AT[AR_DW + blk*(DW_U*128) + idx] = (_Float16)(sm[(RB+r)*DIM+o] + sm[(RB-1)*DIM+o]);
        }
        // shells: RSH = R rows 12..15, DSH = D rows 14..17
        for (int idx = tid; idx < 128; idx += 256) {
            int o = ((idx >> 3) << 1) | ((idx >> 2) & 1), j = idx & 3;
            AT[AR_RSH + blk*128 + idx] = (_Float16)sm[(12 + j)*DIM + o];
            AT[AR_DSH + blk*128 + idx] = (_Float16)sm[(RB + 14 + j)*DIM + o];
        }
    } else if (blk < NTASK) {
        // ---- pos tables
        const int a3 = blk - NPAIR;
        const float* Wlp = Wpl + a3*DIM*DIM;
        for (int idx = tid; idx < PB*DIM; idx += 256) {
            int k = idx >> 5, m = idx & 31;
            E[k*33 + m] = Wpe[k*DIM+m] + bpe[m];
        }
        __syncthreads();
        #pragma unroll
        for (int r = 0; r < 2; ++r) {
            int k  = r*32 + (tid >> 3);
            int oq = (tid & 7) << 2;
            const float* ek = E + k*33;
            float4 a = make_float4(0.f,0.f,0.f,0.f);
            #pragma unroll 8
            for (int m = 0; m < DIM; ++m) {
                float e = ek[m];
                float4 w = *(const float4*)(Wlp + m*DIM + oq);
                a.x = fmaf(e, w.x, a.x); a.y = fmaf(e, w.y, a.y);
                a.z = fmaf(e, w.z, a.z); a.w = fmaf(e, w.w, a.w);
            }
            *(float4*)(sm + k*DIM + oq) = a;
        }
        __syncthreads();
        for (int idx = tid; idx < PW_U*128; idx += 256) {
            int u = idx >> 7, rem = idx & 127;
            int o = ((rem >> 3) << 1) | ((rem >> 2) & 1), j = rem & 3;
            AT[AR_PW + a3*(PW_U*128) + idx] = (_Float16)sm[(2*u + j)*DIM + o];
        }
    } else {
        // ---- G tile: 8 classes x 8 j-columns; aa_emb via uniform s_loads.
        const int gb = blk - NTASK;        // 0..223
        const int cg = gb >> 2, jq = gb & 3;
        const int c0 = cg * 8;
        const int nc = (NCLS - c0 < 8) ? (NCLS - c0) : 8;
        const int h = tid & 127, jh = tid >> 7;
        #pragma unroll
        for (int jj = 0; jj < 4; ++jj) {
            int j = jq*8 + jh*4 + jj;
            float acc[8];
            #pragma unroll
            for (int cc = 0; cc < 8; ++cc) acc[cc] = 0.f;
            #pragma unroll 4
            for (int i = 0; i < DIM; ++i) {
                float w = zW[(size_t)(i*DIM + j)*EDGE + h];
                #pragma unroll
                for (int cc = 0; cc < 8; ++cc) {
                    int cI = c0 + cc; if (cI > NCLS-1) cI = NCLS-1;
                    acc[cc] = fmaf(aa_emb[cI*DIM + i], w, acc[cc]);
                }
            }
            for (int cc = 0; cc < nc; ++cc)
                ws[OFF_G + (size_t)(c0+cc)*DIM*EDGE + j*EDGE + h] = acc[cc];
        }
    }
}

// ---------------------------------------------------------------------------
// 3-bin truncated gaussian softmax, 2-exp relative form: weights proportional
// to {2^(C(2d+1)), 1, 2^(C(1-2d))}, d = u - k0 (center-bin offset).
// Exponent clamp at +80 replaces max-subtraction for clamped-edge bins
// (t*inv -> m exactly; no inf/NaN: exp2(80)=1.2e24, inv ~ 8e-25 normal).
// ---------------------------------------------------------------------------
__device__ __forceinline__ void probs3(float u, int k0, float m, float* pr)
{
    const float C = -18.03368928f;        // -12.5 * log2(e)
    float dd = u - (float)k0;
    float r0 = fminf(C * (2.f*dd + 1.f), 80.f);
    float r2 = fminf(C * (1.f - 2.f*dd), 80.f);
    float t0 = __builtin_exp2f(r0);
    float t2 = __builtin_exp2f(r2);
    float inv = m / (t0 + 1.f + t2);
    pr[0] = t0 * inv; pr[1] = inv; pr[2] = t2 * inv;
}

// rows b..b+2 within the 4-row unit starting at row 2*(b>>1):
// b even -> [w0,w1,w2,0]; b odd -> [0,w0,w1,w2]. Packed as 2x f16-pairs.
__device__ __forceinline__ void packW(const float* w, int b,
                                      unsigned int& wp0, unsigned int& wp1)
{
    if (b & 1) { wp0 = pack2(0.f, w[0]);  wp1 = pack2(w[1], w[2]); }
    else       { wp0 = pack2(w[0], w[1]); wp1 = pack2(w[2], 0.f); }
}

// ---------------------------------------------------------------------------
// struct_fd: one block (256 thr) per pid = blockIdx.x.
// Phase 1 (UNIFIED): the 3-way bin branch computes only {k0, byte-off}
// (if-convertible); the shared probs3+packW+job-store runs ONCE per lane
// (R11 post-mortem: dual-path execution of probs3/packW under divergent
// exec masks was the largest VALU sink). Shell keeps a rare extra-job tail.
// Phase 2: lane l: job-group l>>4, dim-pair l&15; per 16 jobs/wave-iter:
//   1 ds_read_b128 + 1 global dwordx4 + 4 fdot2 (unroll 4).
// Phase 3 (fused): fd in LDS; Z[h] = zb[h] + sum_j fd[j]*G[cls][j][h].
// ---------------------------------------------------------------------------
__global__ __launch_bounds__(256) void struct_fd(
    const int*   __restrict__ aat1,
    const float* __restrict__ pos_a, const float* __restrict__ mask_a,
    const float* __restrict__ pos_b, const float* __restrict__ mask_b,
    const float* __restrict__ rots,  const float* __restrict__ trans,
    const float* __restrict__ brl,   const float* __restrict__ bdl,
    const float* __restrict__ bpl,   const float* __restrict__ zb,
    const float* __restrict__ ws,    float* __restrict__ out)
{
    const int pid = blockIdx.x;
    const int p = pid >> 7, q = pid & 127;
    __shared__ uint4 jobs[MAXJOBS + 16];
    __shared__ int   extCnt[4];
    __shared__ int   extTot;
    __shared__ float sacc[16][DIM];
    __shared__ float fdv[DIM];
    __shared__ float zpart[2][EDGE];
    const int t = threadIdx.x;
    const int lane = t & 63;
    const int wid  = t >> 6;

    bool  flag = false;
    uint4 extraJ = make_uint4(0,0,0,0);

    // ---- Phase 1 ----
    if (t < NTASK) {
        float u, m;
        unsigned off;
        int k0;
        if (t < NPAIR) {
            int i = t / A_, j = t % A_;
            float ax = pos_a[(p*A_+i)*3+0], ay = pos_a[(p*A_+i)*3+1], az = pos_a[(p*A_+i)*3+2];
            float bx = pos_b[(q*A_+j)*3+0], by = pos_b[(q*A_+j)*3+1], bz = pos_b[(q*A_+j)*3+2];
            float dx = bx-ax, dy = by-ay, dz = bz-az;
            float d  = sqrtf(dx*dx + dy*dy + dz*dz);
            m = mask_a[p*A_+i] * mask_b[q*A_+j];
            u = (d - 2.625f) * 0.8f;             // shared off0/s for rough & dist
            int kf = (int)rintf(u);
            bool shell = (kf == RB-1);
            if (kf <= RB-2) {                    // merged rough+dist, rows 0..15
                k0  = max(kf, 1);
                off = ARB_SW + t*(SW_U*256) + ((k0-1)>>1)*256;
            } else if (shell) {                  // main job: R rows 12..15 unit
                k0  = RB-2;
                off = ARB_RSH + t*256;
            } else {                             // far: dist + folded rough edge
                k0  = min(kf, DB-2);
                off = ARB_DW + t*(DW_U*256) + (((k0-1)>>1) - 7)*256;
            }
            if (shell) {                         // rare second job (exact)
                float we[3]; probs3(u, RB-1, m, we);   // D rows 14..16
                unsigned e0, e1;
                packW(we, 14, e0, e1);                 // stored from row 14 (even)
                extraJ = make_uint4(ARB_DSH + t*256, e0, e1, 0);
                flag = true;
            }
        } else {
            int idx = t - NPAIR;
            int a = idx / 3, c = idx % 3;
            float lv = 0.f;
            #pragma unroll
            for (int jr = 0; jr < 3; ++jr)
                lv = fmaf(rots[p*9 + jr*3 + c],
                          pos_b[(q*A_+a)*3 + jr] - trans[p*3 + jr], lv);
            m = mask_b[p*A_+a] * mask_b[q*A_+a];
            u = (lv + 32.f + 0.5f*(64.f/62.f)) * 0.96875f;   // 1/s = 62/64
            k0  = min(max((int)rintf(u), 1), PB-2);
            off = ARB_PW + idx*(PW_U*256) + ((k0-1)>>1)*256;
        }
        // ---- shared: one probs3 + one packW + one job store ----
        float w[3]; probs3(u, k0, m, w);
        unsigned wp0, wp1;
        packW(w, k0-1, wp0, wp1);
        jobs[t] = make_uint4(off, wp0, wp1, 0);
    }
    unsigned long long bal = __ballot(flag);
    if (lane == 0) extCnt[wid] = __popcll(bal);
    int myPos = __popcll(bal & ((1ull << lane) - 1ull));
    __syncthreads();
    if (t == 0) {
        int s = NTASK;
        #pragma unroll
        for (int g = 0; g < 4; ++g) { int c = extCnt[g]; extCnt[g] = s; s += c; }
        extTot = s;
    }
    __syncthreads();
    if (flag) jobs[extCnt[wid] + myPos] = extraJ;
    if (t < 16) {                       // zero-pad to multiple of 16
        int idx = extTot + t;
        if (idx < ((extTot + 15) & ~15)) jobs[idx] = make_uint4(0,0,0,0);
    }
    __syncthreads();

    // ---- Phase 2 ----
    const int g16 = t >> 4;             // job slot within 16-batch
    const int o2  = t & 15;             // dim pair
    const char* Tb = (const char*)(ws + OFF_ARENA);
    const int nj16 = (extTot + 15) & ~15;
    float accA = 0.f, accB = 0.f;
    #pragma unroll 4
    for (int itb = 0; itb < nj16; itb += 16) {
        uint4 J = jobs[itb + g16];
        uint4 v = *(const uint4*)(Tb + J.x + (o2 << 4));
        accA = fdot2f(v.x, J.y, accA);
        accA = fdot2f(v.y, J.z, accA);
        accB = fdot2f(v.z, J.y, accB);
        accB = fdot2f(v.w, J.z, accB);
    }
    sacc[g16][o2*2]   = accA;
    sacc[g16][o2*2+1] = accB;
    __syncthreads();
    if (t < DIM) {
        float v = brl[t] + bdl[t] + bpl[t];
        #pragma unroll
        for (int g = 0; g < 16; ++g) v += sacc[g][t];
        fdv[t] = v;
    }
    __syncthreads();

    // ---- Phase 3 (fused): Z[h] = zb[h] + sum_j fdv[j]*G[cls][j][h] ----
    const int cls = aat1[p]*21 + aat1[q];
    const int h  = t & 127, jh = t >> 7;
    const float* Gp = ws + OFF_G + (size_t)cls*DIM*EDGE + jh*(16*EDGE) + h;
    float zp = 0.f;
    #pragma unroll
    for (int jj = 0; jj < 16; ++jj)
        zp = fmaf(fdv[jh*16 + jj], Gp[jj*EDGE], zp);
    zpart[jh][h] = zp;
    __syncthreads();
    if (t < EDGE)
        out[(size_t)pid*EDGE + t] = zpart[0][t] + zpart[1][t] + zb[t];
}

extern "C" void kernel_launch(void* const* d_in, const int* in_sizes, int n_in,
                              void* d_out, int out_size, void* d_ws, size_t ws_size,
                              hipStream_t stream)
{
    const int*   aat1   = (const int*)  d_in[0];
    const float* pos_a  = (const float*)d_in[2];
    const float* mask_a = (const float*)d_in[3];
    const float* pos_b  = (const float*)d_in[4];
    const float* mask_b = (const float*)d_in[5];
    const float* rots   = (const float*)d_in[6];
    const float* trans  = (const float*)d_in[7];
    const float* aa_emb = (const float*)d_in[8];
    const float* Wre    = (const float*)d_in[9];
    const float* bre    = (const float*)d_in[10];
    const float* Wde    = (const float*)d_in[11];
    const float* bde    = (const float*)d_in[12];
    const float* Wpe    = (const float*)d_in[13];
    const float* bpe    = (const float*)d_in[14];
    const float* Wrl    = (const float*)d_in[15];
    const float* brl    = (const float*)d_in[16];
    const float* Wdl    = (const float*)d_in[17];
    const float* bdl    = (const float*)d_in[18];
    const float* Wpl    = (const float*)d_in[19];
    const float* bpl    = (const float*)d_in[20];
    const float* zW     = (const float*)d_in[21];
    const float* zb     = (const float*)d_in[22];
    float* ws   = (float*)d_ws;
    float* outp = (float*)d_out;

    hipLaunchKernelGGL(preproc, dim3(NPRE), dim3(256), 0, stream,
                       aa_emb, zW,
                       Wre, bre, Wde, bde, Wpe, bpe, Wrl, Wdl, Wpl, ws);
    hipLaunchKernelGGL(struct_fd, dim3(NPID), dim3(256), 0, stream,
                       aat1, pos_a, mask_a, pos_b, mask_b, rots, trans,
                       brl, bdl, bpl, zb, ws, outp);
}

// Round 13
// 73.949 us; speedup vs baseline: 1.2058x; 1.0164x over previous
//
#include <hip/hip_runtime.h>
#include <hip/hip_bf16.h>
#include <math.h>

#define S_   128
#define A_   14
#define DIM  32
#define EDGE 128
#define NPAIR 196         // A*A
#define NPOS  42          // A*3
#define NTASK 238         // NPAIR + NPOS
#define RB 16
#define DB 40
#define PB 64
#define NCLS 441
#define NPID (S_*S_)

// ---- f16 arena: 4-row units. Unit = [o2(16)][d(2)][j(4)] = 128 f16 = 256 B.
// Unit u covers rows rlo..rlo+3; element (o2,d,j) = dim 2*o2+d, row rlo+j.
#define SW_U 7            // rows 2u..2u+3, u=0..6  (R+D rows 0..15)
#define DW_U 12           // rows 14+2u..17+2u      (D rows 14..39, + R[15])
#define PW_U 31           // rows 2u..2u+3          (P rows 0..63)
#define AR_SW   0
#define AR_DW   (AR_SW + NPAIR*SW_U*128)
#define AR_RSH  (AR_DW + NPAIR*DW_U*128)    // R rows 12..15, 1 unit/task
#define AR_DSH  (AR_RSH + NPAIR*128)        // D rows 14..17, 1 unit/task
#define AR_PW   (AR_DSH + NPAIR*128)
#define AR_TOT  (AR_PW + NPOS*PW_U*128)     // 693504 f16 = 1.39 MB

// byte-offset versions (jobs carry byte offsets)
#define ARB_SW  (AR_SW*2)
#define ARB_DW  (AR_DW*2)
#define ARB_RSH (AR_RSH*2)
#define ARB_DSH (AR_DSH*2)
#define ARB_PW  (AR_PW*2)

// ---- ws layout (float units)
#define OFF_G      0
#define OFF_ARENA  (OFF_G + NCLS*DIM*EDGE)     // f16 arena

#define MAXJOBS (NTASK + NPAIR)
#define NGBLK   224        // 56 class-groups (8 cls) x 4 j-quarters
#define NPRE    (NTASK + NGBLK)

// LDS input-staging offsets (floats)
#define SI_PA   0          // pos_a[p]  42
#define SI_PB   42         // pos_b[q]  42
#define SI_MA   84         // mask_a[p] 14
#define SI_MBQ  98         // mask_b[q] 14
#define SI_R    112        // rots[p]   9
#define SI_T    121        // trans[p]  3
#define SI_MBP  124        // mask_b[p] 14
#define SI_TOT  138

typedef _Float16 h2 __attribute__((ext_vector_type(2)));

#if defined(__has_builtin)
#if __has_builtin(__builtin_amdgcn_fdot2)
#define HAVE_FDOT2 1
#endif
#endif

__device__ __forceinline__ float fdot2f(unsigned int a, unsigned int b, float c) {
    h2 ha = __builtin_bit_cast(h2, a), hb = __builtin_bit_cast(h2, b);
#ifdef HAVE_FDOT2
    return __builtin_amdgcn_fdot2(ha, hb, c, false);
#else
    return c + (float)ha[0]*(float)hb[0] + (float)ha[1]*(float)hb[1];
#endif
}

__device__ __forceinline__ unsigned int pack2(float lo, float hi) {
    _Float16 l = (_Float16)lo, h = (_Float16)hi;
    unsigned short lu = __builtin_bit_cast(unsigned short, l);
    unsigned short hu = __builtin_bit_cast(unsigned short, h);
    return (unsigned int)lu | ((unsigned int)hu << 16);
}

// ---------------------------------------------------------------------------
// Fused preprocessing: blocks 0..195 pair tables, 196..237 pos tables,
// 238..461 G (8-class x 8-j tiles, aa_emb via uniform s_loads).
// ---------------------------------------------------------------------------
__global__ __launch_bounds__(256) void preproc(
    const float* __restrict__ aa_emb, const float* __restrict__ zW,
    const float* __restrict__ Wre, const float* __restrict__ bre,
    const float* __restrict__ Wde, const float* __restrict__ bde,
    const float* __restrict__ Wpe, const float* __restrict__ bpe,
    const float* __restrict__ Wrl, const float* __restrict__ Wdl,
    const float* __restrict__ Wpl, float* __restrict__ ws)
{
    __shared__ float sm[64*DIM];          // 8 KB
    __shared__ float E[64*33];            // emb+bias staging (padded)
    const int blk = blockIdx.x;
    const int tid = threadIdx.x;
    _Float16* AT = (_Float16*)(ws + OFF_ARENA);

    if (blk < NPAIR) {
        // ---- pair tables: sm rows 0..15 = R, 16..55 = D
        const float* Wlr = Wrl + blk*DIM*DIM;
        const float* Wld = Wdl + blk*DIM*DIM;
        for (int idx = tid; idx < (RB+DB)*DIM; idx += 256) {
            int k = idx >> 5, m = idx & 31;
            bool isR = k < RB;
            int kk = isR ? k : k - RB;
            E[k*33 + m] = isR ? (Wre[kk*DIM+m] + bre[m]) : (Wde[kk*DIM+m] + bde[m]);
        }
        __syncthreads();
        #pragma unroll
        for (int r = 0; r < 2; ++r) {
            if (tid < 224) {
                int k  = r*28 + (tid >> 3);
                int oq = (tid & 7) << 2;
                const float* Wl = (k < RB) ? Wlr : Wld;
                const float* ek = E + k*33;
                float4 a = make_float4(0.f,0.f,0.f,0.f);
                #pragma unroll 8
                for (int m = 0; m < DIM; ++m) {
                    float e = ek[m];
                    float4 w = *(const float4*)(Wl + m*DIM + oq);
                    a.x = fmaf(e, w.x, a.x); a.y = fmaf(e, w.y, a.y);
                    a.z = fmaf(e, w.z, a.z); a.w = fmaf(e, w.w, a.w);
                }
                *(float4*)(sm + k*DIM + oq) = a;
            }
        }
        __syncthreads();
        // SW units: V = R[r] + D[r], r = 2u+j (0..15)
        for (int idx = tid; idx < SW_U*128; idx += 256) {
            int u = idx >> 7, rem = idx & 127;
            int o = ((rem >> 3) << 1) | ((rem >> 2) & 1), j = rem & 3;
            int r = 2*u + j;
            AT[AR_SW + blk*(SW_U*128) + idx] = (_Float16)(sm[r*DIM+o] + sm[(RB+r)*DIM+o]);
        }
        // DW units: V = D[r] + R[15], r = 14+2u+j (14..39)
        for (int idx = tid; idx < DW_U*128; idx += 256) {
            int u = idx >> 7, rem = idx & 127;
            int o = ((rem >> 3) << 1) | ((rem >> 2) & 1), j = rem & 3;
            int r = 14 + 2*u + j;
            AT[AR_DW + blk*(DW_U*128) + idx] = (_Float16)(sm[(RB+r)*DIM+o] + sm[(RB-1)*DIM+o]);
        }
        // shells: RSH = R rows 12..15, DSH = D rows 14..17
        for (int idx = tid; idx < 128; idx += 256) {
            int o = ((idx >> 3) << 1) | ((idx >> 2) & 1), j = idx & 3;
            AT[AR_RSH + blk*128 + idx] = (_Float16)sm[(12 + j)*DIM + o];
            AT[AR_DSH + blk*128 + idx] = (_Float16)sm[(RB + 14 + j)*DIM + o];
        }
    } else if (blk < NTASK) {
        // ---- pos tables
        const int a3 = blk - NPAIR;
        const float* Wlp = Wpl + a3*DIM*DIM;
        for (int idx = tid; idx < PB*DIM; idx += 256) {
            int k = idx >> 5, m = idx & 31;
            E[k*33 + m] = Wpe[k*DIM+m] + bpe[m];
        }
        __syncthreads();
        #pragma unroll
        for (int r = 0; r < 2; ++r) {
            int k  = r*32 + (tid >> 3);
            int oq = (tid & 7) << 2;
            const float* ek = E + k*33;
            float4 a = make_float4(0.f,0.f,0.f,0.f);
            #pragma unroll 8
            for (int m = 0; m < DIM; ++m) {
                float e = ek[m];
                float4 w = *(const float4*)(Wlp + m*DIM + oq);
                a.x = fmaf(e, w.x, a.x); a.y = fmaf(e, w.y, a.y);
                a.z = fmaf(e, w.z, a.z); a.w = fmaf(e, w.w, a.w);
            }
            *(float4*)(sm + k*DIM + oq) = a;
        }
        __syncthreads();
        for (int idx = tid; idx < PW_U*128; idx += 256) {
            int u = idx >> 7, rem = idx & 127;
            int o = ((rem >> 3) << 1) | ((rem >> 2) & 1), j = rem & 3;
            AT[AR_PW + a3*(PW_U*128) + idx] = (_Float16)sm[(2*u + j)*DIM + o];
        }
    } else {
        // ---- G tile: 8 classes x 8 j-columns; aa_emb via uniform s_loads.
        const int gb = blk - NTASK;        // 0..223
        const int cg = gb >> 2, jq = gb & 3;
        const int c0 = cg * 8;
        const int nc = (NCLS - c0 < 8) ? (NCLS - c0) : 8;
        const int h = tid & 127, jh = tid >> 7;
        #pragma unroll
        for (int jj = 0; jj < 4; ++jj) {
            int j = jq*8 + jh*4 + jj;
            float acc[8];
            #pragma unroll
            for (int cc = 0; cc < 8; ++cc) acc[cc] = 0.f;
            #pragma unroll 4
            for (int i = 0; i < DIM; ++i) {
                float w = zW[(size_t)(i*DIM + j)*EDGE + h];
                #pragma unroll
                for (int cc = 0; cc < 8; ++cc) {
                    int cI = c0 + cc; if (cI > NCLS-1) cI = NCLS-1;
                    acc[cc] = fmaf(aa_emb[cI*DIM + i], w, acc[cc]);
                }
            }
            for (int cc = 0; cc < nc; ++cc)
                ws[OFF_G + (size_t)(c0+cc)*DIM*EDGE + j*EDGE + h] = acc[cc];
        }
    }
}

// ---------------------------------------------------------------------------
// 3-bin truncated gaussian softmax, 2-exp relative form.
// Exponent clamp at +80 replaces max-subtraction for clamped-edge bins.
// ---------------------------------------------------------------------------
__device__ __forceinline__ void probs3(float u, int k0, float m, float* pr)
{
    const float C = -18.03368928f;        // -12.5 * log2(e)
    float dd = u - (float)k0;
    float r0 = fminf(C * (2.f*dd + 1.f), 80.f);
    float r2 = fminf(C * (1.f - 2.f*dd), 80.f);
    float t0 = __builtin_exp2f(r0);
    float t2 = __builtin_exp2f(r2);
    float inv = m / (t0 + 1.f + t2);
    pr[0] = t0 * inv; pr[1] = inv; pr[2] = t2 * inv;
}

// rows b..b+2 within the 4-row unit starting at row 2*(b>>1):
// b even -> [w0,w1,w2,0]; b odd -> [0,w0,w1,w2]. Packed as 2x f16-pairs.
__device__ __forceinline__ void packW(const float* w, int b,
                                      unsigned int& wp0, unsigned int& wp1)
{
    if (b & 1) { wp0 = pack2(0.f, w[0]);  wp1 = pack2(w[1], w[2]); }
    else       { wp0 = pack2(w[0], w[1]); wp1 = pack2(w[2], 0.f); }
}

// ---------------------------------------------------------------------------
// struct_fd: one block (256 thr) per pid = blockIdx.x.
// Phase 0: stage the block's 138 input floats into LDS (coalesced).
// Phase 1 (unified): 3-way bin branch computes only {k0, byte-off};
//   shared probs3+packW+job-store runs once per lane; shell tail rare.
// Phase 2: lane l: job-group l>>4, dim-pair l&15; per 16 jobs/wave-iter:
//   1 ds_read_b128 + 1 global dwordx4 + 4 fdot2 (unroll 4).
// Phase 3 (fused): fd in LDS; Z[h] = zb[h] + sum_j fd[j]*G[cls][j][h].
// ---------------------------------------------------------------------------
__global__ __launch_bounds__(256, 8) void struct_fd(
    const int*   __restrict__ aat1,
    const float* __restrict__ pos_a, const float* __restrict__ mask_a,
    const float* __restrict__ pos_b, const float* __restrict__ mask_b,
    const float* __restrict__ rots,  const float* __restrict__ trans,
    const float* __restrict__ brl,   const float* __restrict__ bdl,
    const float* __restrict__ bpl,   const float* __restrict__ zb,
    const float* __restrict__ ws,    float* __restrict__ out)
{
    const int pid = blockIdx.x;
    const int p = pid >> 7, q = pid & 127;
    __shared__ uint4 jobs[MAXJOBS + 16];
    __shared__ int   extCnt[4];
    __shared__ int   extTot;
    __shared__ float sacc[16][DIM];
    __shared__ float fdv[DIM];
    __shared__ float zpart[2][EDGE];
    __shared__ float sIn[SI_TOT];
    const int t = threadIdx.x;
    const int lane = t & 63;
    const int wid  = t >> 6;

    // ---- Phase 0: stage inputs (coalesced, first 138 lanes) ----
    if (t < NPOS)            sIn[SI_PA  + t] = pos_a[p*NPOS + t];
    else if (t < 2*NPOS)     sIn[SI_PB  + (t-NPOS)] = pos_b[q*NPOS + (t-NPOS)];
    else if (t < 84+A_)      sIn[SI_MA  + (t-84)]  = mask_a[p*A_ + (t-84)];
    else if (t < 98+A_)      sIn[SI_MBQ + (t-98)]  = mask_b[q*A_ + (t-98)];
    else if (t < 112+9)      sIn[SI_R   + (t-112)] = rots[p*9 + (t-112)];
    else if (t < 121+3)      sIn[SI_T   + (t-121)] = trans[p*3 + (t-121)];
    else if (t < 124+A_)     sIn[SI_MBP + (t-124)] = mask_b[p*A_ + (t-124)];
    __syncthreads();

    bool  flag = false;
    uint4 extraJ = make_uint4(0,0,0,0);

    // ---- Phase 1 ----
    if (t < NTASK) {
        float u, m;
        unsigned off;
        int k0;
        if (t < NPAIR) {
            int i = t / A_, j = t % A_;
            float ax = sIn[SI_PA+i*3+0], ay = sIn[SI_PA+i*3+1], az = sIn[SI_PA+i*3+2];
            float bx = sIn[SI_PB+j*3+0], by = sIn[SI_PB+j*3+1], bz = sIn[SI_PB+j*3+2];
            float dx = bx-ax, dy = by-ay, dz = bz-az;
            float d  = sqrtf(dx*dx + dy*dy + dz*dz);
            m = sIn[SI_MA+i] * sIn[SI_MBQ+j];
            u = (d - 2.625f) * 0.8f;             // shared off0/s for rough & dist
            int kf = (int)rintf(u);
            bool shell = (kf == RB-1);
            if (kf <= RB-2) {                    // merged rough+dist, rows 0..15
                k0  = max(kf, 1);
                off = ARB_SW + t*(SW_U*256) + ((k0-1)>>1)*256;
            } else if (shell) {                  // main job: R rows 12..15 unit
                k0  = RB-2;
                off = ARB_RSH + t*256;
            } else {                             // far: dist + folded rough edge
                k0  = min(kf, DB-2);
                off = ARB_DW + t*(DW_U*256) + (((k0-1)>>1) - 7)*256;
            }
            if (shell) {                         // rare second job (exact)
                float we[3]; probs3(u, RB-1, m, we);   // D rows 14..16
                unsigned e0, e1;
                packW(we, 14, e0, e1);                 // stored from row 14 (even)
                extraJ = make_uint4(ARB_DSH + t*256, e0, e1, 0);
                flag = true;
            }
        } else {
            int idx = t - NPAIR;
            int a = idx / 3, c = idx % 3;
            float lv = 0.f;
            #pragma unroll
            for (int jr = 0; jr < 3; ++jr)
                lv = fmaf(sIn[SI_R + jr*3 + c],
                          sIn[SI_PB + a*3 + jr] - sIn[SI_T + jr], lv);
            m = sIn[SI_MBP+a] * sIn[SI_MBQ+a];
            u = (lv + 32.f + 0.5f*(64.f/62.f)) * 0.96875f;   // 1/s = 62/64
            k0  = min(max((int)rintf(u), 1), PB-2);
            off = ARB_PW + idx*(PW_U*256) + ((k0-1)>>1)*256;
        }
        // ---- shared: one probs3 + one packW + one job store ----
        float w[3]; probs3(u, k0, m, w);
        unsigned wp0, wp1;
        packW(w, k0-1, wp0, wp1);
        jobs[t] = make_uint4(off, wp0, wp1, 0);
    }
    unsigned long long bal = __ballot(flag);
    if (lane == 0) extCnt[wid] = __popcll(bal);
    int myPos = __popcll(bal & ((1ull << lane) - 1ull));
    __syncthreads();
    if (t == 0) {
        int s = NTASK;
        #pragma unroll
        for (int g = 0; g < 4; ++g) { int c = extCnt[g]; extCnt[g] = s; s += c; }
        extTot = s;
    }
    __syncthreads();
    if (flag) jobs[extCnt[wid] + myPos] = extraJ;
    if (t < 16) {                       // zero-pad to multiple of 16
        int idx = extTot + t;
        if (idx < ((extTot + 15) & ~15)) jobs[idx] = make_uint4(0,0,0,0);
    }
    __syncthreads();

    // ---- Phase 2 ----
    const int g16 = t >> 4;             // job slot within 16-batch
    const int o2  = t & 15;             // dim pair
    const char* TbL = (const char*)(ws + OFF_ARENA) + (o2 << 4);
    const int nj16 = (extTot + 15) & ~15;
    float accA = 0.f, accB = 0.f;
    #pragma unroll 4
    for (int itb = 0; itb < nj16; itb += 16) {
        uint4 J = jobs[itb + g16];
        uint4 v = *(const uint4*)(TbL + J.x);
        accA = fdot2f(v.x, J.y, accA);
        accA = fdot2f(v.y, J.z, accA);
        accB = fdot2f(v.z, J.y, accB);
        accB = fdot2f(v.w, J.z, accB);
    }
    sacc[g16][o2*2]   = accA;
    sacc[g16][o2*2+1] = accB;
    __syncthreads();
    if (t < DIM) {
        float v = brl[t] + bdl[t] + bpl[t];
        #pragma unroll
        for (int g = 0; g < 16; ++g) v += sacc[g][t];
        fdv[t] = v;
    }
    __syncthreads();

    // ---- Phase 3 (fused): Z[h] = zb[h] + sum_j fdv[j]*G[cls][j][h] ----
    const int cls = aat1[p]*21 + aat1[q];
    const int h  = t & 127, jh = t >> 7;
    const float* Gp = ws + OFF_G + (size_t)cls*DIM*EDGE + jh*(16*EDGE) + h;
    float zp = 0.f;
    #pragma unroll
    for (int jj = 0; jj < 16; ++jj)
        zp = fmaf(fdv[jh*16 + jj], Gp[jj*EDGE], zp);
    zpart[jh][h] = zp;
    __syncthreads();
    if (t < EDGE)
        out[(size_t)pid*EDGE + t] = zpart[0][t] + zpart[1][t] + zb[t];
}

extern "C" void kernel_launch(void* const* d_in, const int* in_sizes, int n_in,
                              void* d_out, int out_size, void* d_ws, size_t ws_size,
                              hipStream_t stream)
{
    const int*   aat1   = (const int*)  d_in[0];
    const float* pos_a  = (const float*)d_in[2];
    const float* mask_a = (const float*)d_in[3];
    const float* pos_b  = (const float*)d_in[4];
    const float* mask_b = (const float*)d_in[5];
    const float* rots   = (const float*)d_in[6];
    const float* trans  = (const float*)d_in[7];
    const float* aa_emb = (const float*)d_in[8];
    const float* Wre    = (const float*)d_in[9];
    const float* bre    = (const float*)d_in[10];
    const float* Wde    = (const float*)d_in[11];
    const float* bde    = (const float*)d_in[12];
    const float* Wpe    = (const float*)d_in[13];
    const float* bpe    = (const float*)d_in[14];
    const float* Wrl    = (const float*)d_in[15];
    const float* brl    = (const float*)d_in[16];
    const float* Wdl    = (const float*)d_in[17];
    const float* bdl    = (const float*)d_in[18];
    const float* Wpl    = (const float*)d_in[19];
    const float* bpl    = (const float*)d_in[20];
    const float* zW     = (const float*)d_in[21];
    const float* zb     = (const float*)d_in[22];
    float* ws   = (float*)d_ws;
    float* outp = (float*)d_out;

    hipLaunchKernelGGL(preproc, dim3(NPRE), dim3(256), 0, stream,
                       aa_emb, zW,
                       Wre, bre, Wde, bde, Wpe, bpe, Wrl, Wdl, Wpl, ws);
    hipLaunchKernelGGL(struct_fd, dim3(NPID), dim3(256), 0, stream,
                       aat1, pos_a, mask_a, pos_b, mask_b, rots, trans,
                       brl, bdl, bpl, zb, ws, outp);
}